// Round 2
// baseline (307.709 us; speedup 1.0000x reference)
//
#include <hip/hip_runtime.h>
#include <stdint.h>

typedef unsigned long long u64;
typedef __attribute__((__vector_size__(16))) float vfloat4;   // native clang vec

#define N_ANCH 100000
#define BATCH 8
#define NTGT 64
#define NFEAT 84
#define BLK 256
#define NWAVE (BLK / 64)
#define APB 1024                          // anchors per block: 4/thread, two pairs
#define NBX ((N_ANCH + APB - 1) / APB)    // 98 blocks per batch
#define GCHUNK (NFEAT / 4)                // 21 float4 per anchor row
#define HALF (APB / 2)                    // 512 rows per gather phase
#define SITER (HALF * GCHUNK / BLK)       // 42 store iterations per half

// Per-anchor registers: xyxy + area + packed tiebreak (~n, larger = smaller n)
struct Anch { float x1, y1, x2, y2, area; u64 pn; };

__device__ __forceinline__ Anch make_anch(float4 ab, int n) {
#pragma clang fp contract(off)
    Anch a;
    a.x1 = ab.x - ab.z * 0.5f;
    a.y1 = ab.y - ab.w * 0.5f;
    a.x2 = ab.x + ab.z * 0.5f;
    a.y2 = ab.y + ab.w * 0.5f;
    a.area = (a.x2 - a.x1) * (a.y2 - a.y1);        // numpy op order
    a.pn = (u64)(0xFFFFFFFFu - (uint32_t)n);
    return a;
}

// Exact reference op order; IEEE division (argmax ties must match bit-for-bit).
__device__ __forceinline__ uint32_t iou_bits(const Anch& a, float4 tb, float areaB) {
#pragma clang fp contract(off)
    const float w = fmaxf(fminf(a.x2, tb.z) - fmaxf(a.x1, tb.x), 0.0f);
    const float h = fmaxf(fminf(a.y2, tb.w) - fmaxf(a.y1, tb.y), 0.0f);
    const float inter = w * h;
    const float iou = inter / (((a.area + areaB) - inter) + 1e-9f);
    return __float_as_uint(iou);                   // iou >= 0: bits monotone
}

// One staggered step for a pair of anchors: 2 IoUs per ds_read pair, ONE LDS
// atomic (pair pre-max; pn ordering keeps smallest-n tiebreak exact).
template <bool FULL>
__device__ __forceinline__ void pair_step(
    int t, const Anch& A, const Anch& B, bool vA, bool vB,
    const float4* __restrict__ tbox, const float* __restrict__ sarea,
    u64* __restrict__ slot, u64& bestA, u64& bestB)
{
    const float4 tb   = tbox[t];                   // ds_read_b128, conflict-free
    const float areaB = sarea[t];
    const uint32_t ia = iou_bits(A, tb, areaB);
    const uint32_t ib = iou_bits(B, tb, areaB);
    const u64 lowt = (u64)(63 - t);                // ties -> smallest t
    const u64 pa = ((u64)ia << 32) | lowt;
    const u64 pb = ((u64)ib << 32) | lowt;
    bestA = pa > bestA ? pa : bestA;
    bestB = pb > bestB ? pb : bestB;
    u64 cA = ((u64)ia << 32) | A.pn;
    u64 cB = ((u64)ib << 32) | B.pn;
    if (!FULL) { if (!vA) cA = 0ull; if (!vB) cB = 0ull; }
    const u64 c = cA > cB ? cA : cB;               // pn(A) > pn(B): smaller n wins ties
    atomicMax(slot + t, c);                        // native ds_max_u64, distinct slot/lane
}

__device__ __forceinline__ void write_masks(u64 best, int b, int n,
                                            float* __restrict__ out_fore,
                                            float* __restrict__ out_back)
{
    const float mi = __uint_as_float((uint32_t)(best >> 32));
    const bool fore = (mi >= 0.5f);
    const bool back = (!fore) && (mi < 0.4f);
    const size_t o = (size_t)b * N_ANCH + n;
    out_fore[o] = fore ? 1.0f : 0.0f;
    out_back[o] = back ? 1.0f : 0.0f;
}

// One coalesced gather-store iteration: out address is exactly outp + 16*i
// (since NFEAT = 4*GCHUNK); labels rows are L1-resident. Nontemporal: the
// 268.8 MB stream is never re-read.
template <bool FULL>
__device__ __forceinline__ void gather_iter(
    int j, int tid, int arow0, const int* __restrict__ sidx,
    const float* __restrict__ lab_b, float* __restrict__ outp)
{
    const int i  = j * BLK + tid;
    const int nl = i / GCHUNK;
    const int k  = i - nl * GCHUNK;
    if (FULL || (arow0 + nl < N_ANCH)) {
        const int t = sidx[nl];
        const vfloat4 v = *(const vfloat4*)(lab_b + (size_t)t * NFEAT + (size_t)k * 4);
        __builtin_nontemporal_store(v, (vfloat4*)(outp + (size_t)i * 4));
    }
}

template <bool FULL>
__device__ __forceinline__ void block_body(
    int b, int bx, int tid, int wave,
    const float* __restrict__ labels, const float* __restrict__ anchors,
    float* __restrict__ out_fore, float* __restrict__ out_back,
    float* __restrict__ out_assigned, u64* __restrict__ ws_part,
    const float4* __restrict__ tbox, const float* __restrict__ sarea,
    u64* __restrict__ board, int* __restrict__ sidx)
{
    const int base = bx * APB;
    const int nA0 = base + tid,        nA1 = base + 256 + tid;   // pair0: rows [0,512)
    const int nB0 = base + 512 + tid,  nB1 = base + 768 + tid;   // pair1: rows [512,1024)
    const bool vA0 = FULL || (nA0 < N_ANCH);
    const bool vA1 = FULL || (nA1 < N_ANCH);
    const bool vB0 = FULL || (nB0 < N_ANCH);
    const bool vB1 = FULL || (nB1 < N_ANCH);

    // Issue all 4 anchor loads up front (hide global latency under loop1).
    const float4 rA0 = *(const float4*)(anchors + (size_t)(vA0 ? nA0 : 0) * 4);
    const float4 rA1 = *(const float4*)(anchors + (size_t)(vA1 ? nA1 : 0) * 4);
    const float4 rB0 = *(const float4*)(anchors + (size_t)(vB0 ? nB0 : 0) * 4);
    const float4 rB1 = *(const float4*)(anchors + (size_t)(vB1 ? nB1 : 0) * 4);

    u64* slot = board + (size_t)wave * NTGT;

    // ---- phase 1: compute pair0 ----
    const Anch A0 = make_anch(rA0, nA0), A1 = make_anch(rA1, nA1);
    u64 bA0 = 0ull, bA1 = 0ull;
    int t = tid & (NTGT - 1);                      // staggered: distinct t per lane
#pragma unroll 4
    for (int s = 0; s < NTGT; ++s) {
        pair_step<FULL>(t, A0, A1, vA0, vA1, tbox, sarea, slot, bA0, bA1);
        t = (t + 1) & (NTGT - 1);
    }

    if (vA0) { write_masks(bA0, b, nA0, out_fore, out_back);
               sidx[tid]       = 63 - (int)(bA0 & 0xFFFFFFFFull); }
    else       sidx[tid]       = 0;
    if (vA1) { write_masks(bA1, b, nA1, out_fore, out_back);
               sidx[256 + tid] = 63 - (int)(bA1 & 0xFFFFFFFFull); }
    else       sidx[256 + tid] = 0;
    __syncthreads();

    // ---- phase 2: compute pair1 WITH pair0's gather stores interleaved ----
    // 21 groups x {3 IoU steps + 2 store iters} + 1 final step = 64 steps, 42 stores.
    const Anch B0 = make_anch(rB0, nB0), B1 = make_anch(rB1, nB1);
    u64 bB0 = 0ull, bB1 = 0ull;
    const float* lab_b = labels + (size_t)b * NTGT * NFEAT;
    float* out0 = out_assigned + ((size_t)b * N_ANCH + base) * NFEAT;

    t = tid & (NTGT - 1);
    for (int g = 0; g < 21; ++g) {
        pair_step<FULL>(t, B0, B1, vB0, vB1, tbox, sarea, slot, bB0, bB1);
        t = (t + 1) & (NTGT - 1);
        pair_step<FULL>(t, B0, B1, vB0, vB1, tbox, sarea, slot, bB0, bB1);
        t = (t + 1) & (NTGT - 1);
        pair_step<FULL>(t, B0, B1, vB0, vB1, tbox, sarea, slot, bB0, bB1);
        t = (t + 1) & (NTGT - 1);
        gather_iter<FULL>(2 * g,     tid, base, sidx, lab_b, out0);
        gather_iter<FULL>(2 * g + 1, tid, base, sidx, lab_b, out0);
    }
    pair_step<FULL>(t, B0, B1, vB0, vB1, tbox, sarea, slot, bB0, bB1);  // step 64

    if (vB0) { write_masks(bB0, b, nB0, out_fore, out_back);
               sidx[512 + tid] = 63 - (int)(bB0 & 0xFFFFFFFFull); }
    else       sidx[512 + tid] = 0;
    if (vB1) { write_masks(bB1, b, nB1, out_fore, out_back);
               sidx[768 + tid] = 63 - (int)(bB1 & 0xFFFFFFFFull); }
    else       sidx[768 + tid] = 0;
    __syncthreads();

    // merge 4 wave-boards -> one partial per (b,t,block); [b][t][blk] layout
    if (tid < NTGT) {
        const u64 m0 = board[tid];
        const u64 m1 = board[NTGT + tid];
        const u64 m2 = board[2 * NTGT + tid];
        const u64 m3 = board[3 * NTGT + tid];
        const u64 a = m0 > m1 ? m0 : m1;
        const u64 c = m2 > m3 ? m2 : m3;
        ws_part[((size_t)b * NTGT + tid) * NBX + bx] = a > c ? a : c;
    }

    // ---- phase 3: tail gather for pair1 ----
    float* out1 = out_assigned + ((size_t)b * N_ANCH + base + HALF) * NFEAT;
    const int* sidx1 = sidx + HALF;
#pragma unroll 2
    for (int j = 0; j < SITER; ++j)
        gather_iter<FULL>(j, tid, base + HALF, sidx1, lab_b, out1);
}

// ---------------------------------------------------------------------------
// Fused kernel: IoU + masks + per-target partial argmax + assigned gather,
// software-pipelined so gather stores overlap the second IoU loop.
// ---------------------------------------------------------------------------
__global__ __launch_bounds__(BLK) void fused_kernel(
    const float* __restrict__ labels,    // [B, NTGT, NFEAT]
    const float* __restrict__ anchors,   // [N_ANCH, 4] cxcywh
    float* __restrict__ out_fore,        // [B, N_ANCH]
    float* __restrict__ out_back,        // [B, N_ANCH]
    float* __restrict__ out_assigned,    // [B, N_ANCH, NFEAT]
    u64* __restrict__ ws_part)           // [B, NTGT, NBX]
{
#pragma clang fp contract(off)
    __shared__ float4 tbox[NTGT];                 // xyxy
    __shared__ float  sarea[NTGT];
    __shared__ u64    board[NWAVE * NTGT];        // per-wave winners
    __shared__ int    sidx[APB];

    const int b    = blockIdx.y;
    const int bx   = blockIdx.x;
    const int tid  = threadIdx.x;
    const int wave = tid >> 6;

    if (tid < NTGT) {
        const float4 box = *(const float4*)(labels + ((size_t)b * NTGT + tid) * NFEAT);
        const float x1 = box.x - box.z * 0.5f;
        const float y1 = box.y - box.w * 0.5f;
        const float x2 = box.x + box.z * 0.5f;
        const float y2 = box.y + box.w * 0.5f;
        tbox[tid]  = make_float4(x1, y1, x2, y2);
        sarea[tid] = (x2 - x1) * (y2 - y1);       // numpy op order
    }
    board[tid] = 0ull;                            // NWAVE*NTGT == BLK
    __syncthreads();

    if (bx != NBX - 1) {                          // uniform branch
        block_body<true >(b, bx, tid, wave, labels, anchors, out_fore, out_back,
                          out_assigned, ws_part, tbox, sarea, board, sidx);
    } else {
        block_body<false>(b, bx, tid, wave, labels, anchors, out_fore, out_back,
                          out_assigned, ws_part, tbox, sarea, board, sidx);
    }
}

// ---------------------------------------------------------------------------
// Fixup: one wave per (b,t); coalesced reads of [b][t][0..NBX); shuffle-max;
// scatter fore=1 / back=0 at best anchor (idempotent, replicates .at[].set).
// ---------------------------------------------------------------------------
__global__ __launch_bounds__(64) void fixup_kernel(
    const u64* __restrict__ ws_part,   // [B, NTGT, NBX]
    float* __restrict__ out_fore,
    float* __restrict__ out_back)
{
    const int bt   = blockIdx.x;     // 0..B*NTGT-1
    const int lane = threadIdx.x;    // 0..63
    const u64* p = ws_part + (size_t)bt * NBX;

    u64 best = 0ull;
    for (int i = lane; i < NBX; i += 64) {               // 2 coalesced rounds
        const u64 v = p[i];
        best = v > best ? v : best;
    }
    for (int off = 32; off > 0; off >>= 1) {
        const u64 o = __shfl_down(best, off, 64);
        best = o > best ? o : best;
    }
    if (lane == 0) {
        const uint32_t n = 0xFFFFFFFFu - (uint32_t)(best & 0xFFFFFFFFull);
        const int b = bt >> 6;
        const size_t o = (size_t)b * N_ANCH + n;
        out_fore[o] = 1.0f;
        out_back[o] = 0.0f;
    }
}

extern "C" void kernel_launch(void* const* d_in, const int* in_sizes, int n_in,
                              void* d_out, int out_size, void* d_ws, size_t ws_size,
                              hipStream_t stream) {
    const float* labels  = (const float*)d_in[0];   // (8, 64, 84) f32
    const float* anchors = (const float*)d_in[1];   // (1, 100000, 4) f32

    float* out_fore     = (float*)d_out;                         // B*N
    float* out_back     = out_fore + (size_t)BATCH * N_ANCH;     // B*N
    float* out_assigned = out_back + (size_t)BATCH * N_ANCH;     // B*N*84

    u64* ws_part = (u64*)d_ws;                                   // B*NTGT*NBX u64

    dim3 gridA(NBX, BATCH);
    fused_kernel<<<gridA, BLK, 0, stream>>>(labels, anchors, out_fore, out_back,
                                            out_assigned, ws_part);

    fixup_kernel<<<BATCH * NTGT, 64, 0, stream>>>(ws_part, out_fore, out_back);
}

// Round 3
// 291.687 us; speedup vs baseline: 1.0549x; 1.0549x over previous
//
#include <hip/hip_runtime.h>
#include <stdint.h>

typedef unsigned long long u64;

#define N_ANCH 100000
#define BATCH 8
#define NTGT 64
#define NFEAT 84
#define BLK 256
#define NWAVE (BLK / 64)
#define APB 512                           // anchors per block: 2/thread (one pair)
#define NBX ((N_ANCH + APB - 1) / APB)    // 196 blocks per batch
#define GCHUNK (NFEAT / 4)                // 21 float4 per anchor row
#define SITER (APB * GCHUNK / BLK)        // 42 gather-store iterations

// Per-anchor registers: xyxy + area + packed tiebreak (~n, larger = smaller n)
struct Anch { float x1, y1, x2, y2, area; u64 pn; };

__device__ __forceinline__ Anch make_anch(float4 ab, int n) {
#pragma clang fp contract(off)
    Anch a;
    a.x1 = ab.x - ab.z * 0.5f;
    a.y1 = ab.y - ab.w * 0.5f;
    a.x2 = ab.x + ab.z * 0.5f;
    a.y2 = ab.y + ab.w * 0.5f;
    a.area = (a.x2 - a.x1) * (a.y2 - a.y1);        // numpy op order
    a.pn = (u64)(0xFFFFFFFFu - (uint32_t)n);
    return a;
}

// Exact reference op order; IEEE division (argmax ties must match bit-for-bit).
__device__ __forceinline__ uint32_t iou_bits(const Anch& a, float4 tb, float areaB) {
#pragma clang fp contract(off)
    const float w = fmaxf(fminf(a.x2, tb.z) - fmaxf(a.x1, tb.x), 0.0f);
    const float h = fmaxf(fminf(a.y2, tb.w) - fmaxf(a.y1, tb.y), 0.0f);
    const float inter = w * h;
    const float iou = inter / (((a.area + areaB) - inter) + 1e-9f);
    return __float_as_uint(iou);                   // iou >= 0: bits monotone
}

// One staggered step for a pair of anchors: one ds_read_b128 + one ds_read_b32
// + ONE ds_atomic serve TWO IoUs (DS-pipe cycles per IoU halved vs 1-anchor).
// pn ordering keeps the smallest-n tiebreak exact under the pair pre-max.
template <bool FULL>
__device__ __forceinline__ void pair_step(
    int t, const Anch& A, const Anch& B, bool vA, bool vB,
    const float4* __restrict__ tbox, const float* __restrict__ sarea,
    u64* __restrict__ slot, u64& bestA, u64& bestB)
{
    const float4 tb   = tbox[t];                   // ds_read_b128, conflict-free
    const float areaB = sarea[t];
    const uint32_t ia = iou_bits(A, tb, areaB);
    const uint32_t ib = iou_bits(B, tb, areaB);
    const u64 lowt = (u64)(63 - t);                // ties -> smallest t
    const u64 pa = ((u64)ia << 32) | lowt;
    const u64 pb = ((u64)ib << 32) | lowt;
    bestA = pa > bestA ? pa : bestA;
    bestB = pb > bestB ? pb : bestB;
    u64 cA = ((u64)ia << 32) | A.pn;
    u64 cB = ((u64)ib << 32) | B.pn;
    if (!FULL) { if (!vA) cA = 0ull; if (!vB) cB = 0ull; }
    const u64 c = cA > cB ? cA : cB;               // pn(A) > pn(B): smaller n wins ties
    atomicMax(slot + t, c);                        // native ds_max_u64, distinct slot/lane
}

__device__ __forceinline__ void write_masks(u64 best, int b, int n,
                                            float* __restrict__ out_fore,
                                            float* __restrict__ out_back)
{
    const float mi = __uint_as_float((uint32_t)(best >> 32));
    const bool fore = (mi >= 0.5f);
    const bool back = (!fore) && (mi < 0.4f);
    const size_t o = (size_t)b * N_ANCH + n;
    out_fore[o] = fore ? 1.0f : 0.0f;
    out_back[o] = back ? 1.0f : 0.0f;
}

template <bool FULL>
__device__ __forceinline__ void block_body(
    int b, int bx, int tid, int wave,
    const float* __restrict__ labels, const float* __restrict__ anchors,
    float* __restrict__ out_fore, float* __restrict__ out_back,
    float* __restrict__ out_assigned, u64* __restrict__ ws_part,
    const float4* __restrict__ tbox, const float* __restrict__ sarea,
    u64* __restrict__ board, int* __restrict__ sidx)
{
    const int base = bx * APB;
    const int nA = base + tid;             // rows [0,256)
    const int nB = base + 256 + tid;       // rows [256,512)
    const bool vA = FULL || (nA < N_ANCH);
    const bool vB = FULL || (nB < N_ANCH);

    // Issue both anchor loads up front (hide global latency under setup).
    const float4 rA = *(const float4*)(anchors + (size_t)(vA ? nA : 0) * 4);
    const float4 rB = *(const float4*)(anchors + (size_t)(vB ? nB : 0) * 4);

    u64* slot = board + (size_t)wave * NTGT;

    const Anch A = make_anch(rA, nA), B = make_anch(rB, nB);
    u64 bA = 0ull, bB = 0ull;
    int t = tid & (NTGT - 1);                      // staggered: distinct t per lane
#pragma unroll 4
    for (int s = 0; s < NTGT; ++s) {
        pair_step<FULL>(t, A, B, vA, vB, tbox, sarea, slot, bA, bB);
        t = (t + 1) & (NTGT - 1);
    }

    if (vA) { write_masks(bA, b, nA, out_fore, out_back);
              sidx[tid]       = 63 - (int)(bA & 0xFFFFFFFFull); }
    else      sidx[tid]       = 0;
    if (vB) { write_masks(bB, b, nB, out_fore, out_back);
              sidx[256 + tid] = 63 - (int)(bB & 0xFFFFFFFFull); }
    else      sidx[256 + tid] = 0;
    __syncthreads();

    // merge 4 wave-boards -> one partial per (b,t,block); [b][t][blk] layout
    if (tid < NTGT) {
        const u64 m0 = board[tid];
        const u64 m1 = board[NTGT + tid];
        const u64 m2 = board[2 * NTGT + tid];
        const u64 m3 = board[3 * NTGT + tid];
        const u64 a = m0 > m1 ? m0 : m1;
        const u64 c = m2 > m3 ? m2 : m3;
        ws_part[((size_t)b * NTGT + tid) * NBX + bx] = a > c ? a : c;
    }

    // gather epilogue: coalesced float4 stores; labels rows are L1-resident
    const float* lab_b = labels + (size_t)b * NTGT * NFEAT;
    float* out_b = out_assigned + ((size_t)b * N_ANCH + base) * NFEAT;
    for (int j = 0; j < SITER; ++j) {              // 42 iterations
        const int i  = j * BLK + tid;
        const int nl = i / GCHUNK;
        const int k  = i - nl * GCHUNK;
        if (FULL || (base + nl < N_ANCH)) {
            const int tt = sidx[nl];
            const float4 v = *(const float4*)(lab_b + (size_t)tt * NFEAT + (size_t)k * 4);
            *(float4*)(out_b + (size_t)i * 4) = v;
        }
    }
}

// ---------------------------------------------------------------------------
// Fused kernel: IoU + masks + per-target partial argmax + assigned gather.
// ---------------------------------------------------------------------------
__global__ __launch_bounds__(BLK) void fused_kernel(
    const float* __restrict__ labels,    // [B, NTGT, NFEAT]
    const float* __restrict__ anchors,   // [N_ANCH, 4] cxcywh
    float* __restrict__ out_fore,        // [B, N_ANCH]
    float* __restrict__ out_back,        // [B, N_ANCH]
    float* __restrict__ out_assigned,    // [B, N_ANCH, NFEAT]
    u64* __restrict__ ws_part)           // [B, NTGT, NBX]
{
#pragma clang fp contract(off)
    __shared__ float4 tbox[NTGT];                 // xyxy
    __shared__ float  sarea[NTGT];
    __shared__ u64    board[NWAVE * NTGT];        // per-wave winners
    __shared__ int    sidx[APB];

    const int b    = blockIdx.y;
    const int bx   = blockIdx.x;
    const int tid  = threadIdx.x;
    const int wave = tid >> 6;

    if (tid < NTGT) {
        const float4 box = *(const float4*)(labels + ((size_t)b * NTGT + tid) * NFEAT);
        const float x1 = box.x - box.z * 0.5f;
        const float y1 = box.y - box.w * 0.5f;
        const float x2 = box.x + box.z * 0.5f;
        const float y2 = box.y + box.w * 0.5f;
        tbox[tid]  = make_float4(x1, y1, x2, y2);
        sarea[tid] = (x2 - x1) * (y2 - y1);       // numpy op order
    }
    board[tid] = 0ull;                            // NWAVE*NTGT == BLK
    __syncthreads();

    if (bx != NBX - 1) {                          // uniform branch
        block_body<true >(b, bx, tid, wave, labels, anchors, out_fore, out_back,
                          out_assigned, ws_part, tbox, sarea, board, sidx);
    } else {
        block_body<false>(b, bx, tid, wave, labels, anchors, out_fore, out_back,
                          out_assigned, ws_part, tbox, sarea, board, sidx);
    }
}

// ---------------------------------------------------------------------------
// Fixup: one wave per (b,t); coalesced reads of [b][t][0..NBX); shuffle-max;
// scatter fore=1 / back=0 at best anchor (idempotent, replicates .at[].set).
// ---------------------------------------------------------------------------
__global__ __launch_bounds__(64) void fixup_kernel(
    const u64* __restrict__ ws_part,   // [B, NTGT, NBX]
    float* __restrict__ out_fore,
    float* __restrict__ out_back)
{
    const int bt   = blockIdx.x;     // 0..B*NTGT-1
    const int lane = threadIdx.x;    // 0..63
    const u64* p = ws_part + (size_t)bt * NBX;

    u64 best = 0ull;
    for (int i = lane; i < NBX; i += 64) {               // 4 coalesced rounds
        const u64 v = p[i];
        best = v > best ? v : best;
    }
    for (int off = 32; off > 0; off >>= 1) {
        const u64 o = __shfl_down(best, off, 64);
        best = o > best ? o : best;
    }
    if (lane == 0) {
        const uint32_t n = 0xFFFFFFFFu - (uint32_t)(best & 0xFFFFFFFFull);
        const int b = bt >> 6;
        const size_t o = (size_t)b * N_ANCH + n;
        out_fore[o] = 1.0f;
        out_back[o] = 0.0f;
    }
}

extern "C" void kernel_launch(void* const* d_in, const int* in_sizes, int n_in,
                              void* d_out, int out_size, void* d_ws, size_t ws_size,
                              hipStream_t stream) {
    const float* labels  = (const float*)d_in[0];   // (8, 64, 84) f32
    const float* anchors = (const float*)d_in[1];   // (1, 100000, 4) f32

    float* out_fore     = (float*)d_out;                         // B*N
    float* out_back     = out_fore + (size_t)BATCH * N_ANCH;     // B*N
    float* out_assigned = out_back + (size_t)BATCH * N_ANCH;     // B*N*84

    u64* ws_part = (u64*)d_ws;                                   // B*NTGT*NBX u64

    dim3 gridA(NBX, BATCH);
    fused_kernel<<<gridA, BLK, 0, stream>>>(labels, anchors, out_fore, out_back,
                                            out_assigned, ws_part);

    fixup_kernel<<<BATCH * NTGT, 64, 0, stream>>>(ws_part, out_fore, out_back);
}